// Round 1
// baseline (303.493 us; speedup 1.0000x reference)
//
#include <hip/hip_runtime.h>

#define HH 128
#define WW 128
#define CIN 64
#define COUT 64
#define NB 8

// -------------------------------------------------------------------------
// Kernel 1: offset conv  off[b,j,y,x] = sum_{c,ky,kx} x[b,c,y+ky-1,x+kx-1]*ow[j,c,ky,kx] + obias[j]
// one pixel per thread (6 outputs), offset_w staged in LDS as [c][t][j]
// -------------------------------------------------------------------------
__global__ __launch_bounds__(256) void offset_kernel(const float* __restrict__ x,
                                                     const float* __restrict__ ow,
                                                     const float* __restrict__ obias,
                                                     float* __restrict__ off) {
    __shared__ float lw[CIN * 9 * 6];   // [c][t][j], 13.5 KB
    const int tid = threadIdx.x;
    for (int i = tid; i < CIN * 9 * 6; i += 256) {
        int j = i % 6;
        int t = (i / 6) % 9;
        int c = i / 54;
        lw[i] = ow[(j * CIN + c) * 9 + t];
    }
    __syncthreads();

    const int blk = blockIdx.x;          // b*64 + rowpair
    const int b   = blk >> 6;
    const int y   = ((blk & 63) << 1) + (tid >> 7);
    const int xq  = tid & 127;

    const float* xb = x + (size_t)b * CIN * HH * WW;

    float acc[6];
#pragma unroll
    for (int j = 0; j < 6; ++j) acc[j] = obias[j];

    for (int c = 0; c < CIN; ++c) {
        const float* xc = xb + c * HH * WW;
        float v[9];
#pragma unroll
        for (int dy = -1; dy <= 1; ++dy) {
            int yy = y + dy;
            bool yv = (yy >= 0) && (yy < HH);
            int ycl = min(max(yy, 0), HH - 1);
#pragma unroll
            for (int dx = -1; dx <= 1; ++dx) {
                int xx = xq + dx;
                bool xv = (xx >= 0) && (xx < WW);
                int xcl = min(max(xx, 0), WW - 1);
                float val = xc[ycl * WW + xcl];
                v[(dy + 1) * 3 + (dx + 1)] = (yv && xv) ? val : 0.f;
            }
        }
#pragma unroll
        for (int t = 0; t < 9; ++t) {
            const float* wp = &lw[(c * 9 + t) * 6];
#pragma unroll
            for (int j = 0; j < 6; ++j) acc[j] += v[t] * wp[j];
        }
    }
#pragma unroll
    for (int j = 0; j < 6; ++j)
        off[(((size_t)b * 6 + j) * HH + y) * WW + xq] = acc[j];
}

// -------------------------------------------------------------------------
// Kernel 2: deformable strip conv.
// One pixel per thread, 64 fp32 accumulators. Weights staged in LDS per
// phase as [k][c][o] (48 KB). Each (k,c) sample is a 2-point lerp (the
// non-deformed coordinate is exactly integer so two bilinear corners have
// zero weight).
// -------------------------------------------------------------------------
__global__ __launch_bounds__(256) void main_kernel(const float* __restrict__ x,
                                                   const float* __restrict__ off,
                                                   const float* __restrict__ wh,
                                                   const float* __restrict__ wv,
                                                   float* __restrict__ out) {
    __shared__ float lw[3 * CIN * COUT];   // [k][c][o], 48 KB

    const int tid = threadIdx.x;
    const int blk = blockIdx.x;          // b*64 + rowpair
    const int b   = blk >> 6;
    const int y   = ((blk & 63) << 1) + (tid >> 7);
    const int xq  = tid & 127;

    const float* xb   = x   + (size_t)b * CIN * HH * WW;
    const float* offb = off + (size_t)b * 6 * HH * WW;

    float acc[COUT];
#pragma unroll
    for (int o = 0; o < COUT; ++o) acc[o] = 0.f;

#pragma unroll
    for (int phase = 0; phase < 2; ++phase) {
        const float* wsrc = phase ? wv : wh;
        __syncthreads();   // protect previous phase's LDS reads
        for (int i = tid; i < 3 * CIN * COUT; i += 256) {
            int o = i & 63;
            int c = (i >> 6) & 63;
            int k = i >> 12;
            // w_h: (O, C, 1, K) and w_v: (O, C, K, 1) flatten identically
            lw[i] = wsrc[(o * CIN + c) * 3 + k];
        }
        __syncthreads();

        for (int k = 0; k < 3; ++k) {
            float o1 = offb[((phase * 3 + k) * HH + y) * WW + xq];
            float wA, wB;
            int idxA, idxB;
            if (phase == 0) {
                // horizontal: py = y + off (fractional), px = x + k - 1 (integer)
                float py  = (float)y + o1;
                float y0f = floorf(py);
                float wy  = py - y0f;
                int   y0  = (int)y0f;
                bool v0 = (y0 >= 0) && (y0 <= HH - 1);
                bool v1 = (y0 + 1 >= 0) && (y0 + 1 <= HH - 1);
                int   px = xq + k - 1;
                bool pv = (px >= 0) && (px <= WW - 1);
                wA = (pv && v0) ? (1.f - wy) : 0.f;
                wB = (pv && v1) ? wy : 0.f;
                int ra = min(max(y0, 0), HH - 1);
                int rb = min(max(y0 + 1, 0), HH - 1);
                int ca = min(max(px, 0), WW - 1);
                idxA = ra * WW + ca;
                idxB = rb * WW + ca;
            } else {
                // vertical: py = y + k - 1 (integer), px = x + off (fractional)
                float px  = (float)xq + o1;
                float x0f = floorf(px);
                float wx  = px - x0f;
                int   x0  = (int)x0f;
                bool v0 = (x0 >= 0) && (x0 <= WW - 1);
                bool v1 = (x0 + 1 >= 0) && (x0 + 1 <= WW - 1);
                int   py = y + k - 1;
                bool pv = (py >= 0) && (py <= HH - 1);
                wA = (pv && v0) ? (1.f - wx) : 0.f;
                wB = (pv && v1) ? wx : 0.f;
                int ra = min(max(py, 0), HH - 1);
                int ca = min(max(x0, 0), WW - 1);
                int cb = min(max(x0 + 1, 0), WW - 1);
                idxA = ra * WW + ca;
                idxB = ra * WW + cb;
            }

            const float4* lwk = (const float4*)&lw[k * CIN * COUT];
            for (int c = 0; c < CIN; ++c) {
                const float* xc = xb + c * HH * WW;
                float v = wA * xc[idxA] + wB * xc[idxB];
                const float4* wp = lwk + c * 16;
#pragma unroll
                for (int q = 0; q < 16; ++q) {
                    float4 w4 = wp[q];
                    acc[4 * q + 0] += v * w4.x;
                    acc[4 * q + 1] += v * w4.y;
                    acc[4 * q + 2] += v * w4.z;
                    acc[4 * q + 3] += v * w4.w;
                }
            }
        }
    }

    float* op = out + ((size_t)b * COUT * HH) * WW + y * WW + xq;
#pragma unroll
    for (int o = 0; o < COUT; ++o) op[o * HH * WW] = acc[o];
}

extern "C" void kernel_launch(void* const* d_in, const int* in_sizes, int n_in,
                              void* d_out, int out_size, void* d_ws, size_t ws_size,
                              hipStream_t stream) {
    const float* x     = (const float*)d_in[0];
    const float* ow    = (const float*)d_in[1];
    const float* obias = (const float*)d_in[2];
    const float* wh    = (const float*)d_in[3];
    const float* wv    = (const float*)d_in[4];
    float* out = (float*)d_out;
    float* off = (float*)d_ws;   // 8*6*128*128 floats = 3.1 MB scratch

    dim3 grid(NB * (HH / 2));    // 512 blocks: b*64 + rowpair
    dim3 block(256);             // 2 rows x 128 cols, one pixel per thread
    offset_kernel<<<grid, block, 0, stream>>>(x, ow, obias, off);
    main_kernel<<<grid, block, 0, stream>>>(x, off, wh, wv, out);
}